// Round 3
// baseline (387.241 us; speedup 1.0000x reference)
//
#include <hip/hip_runtime.h>
#include <cstdint>
#include <cstddef>

#define BATCH 32
#define IMH 512
#define IMW 512
#define KMAX 256
#define CAP 49152        // per-image candidate capacity (expected ~29k)
#define SURV_CAP 8192    // per-image survivor capacity (expected ~300-600)
#define NB 4096          // histogram bins: key bits [63:52] (sign|exp|3 mantissa)

// K1 tiling: 64x32 pixels per 256-thread block
#define TW 64
#define TH 32
#define LCAP 2048
#define SCW 72           // LDS row stride: halo-left at col 3, interior 4..67, halo-right 68

typedef unsigned long long u64;

__device__ __forceinline__ float sigmoidf_(float x) {
    return 1.0f / (1.0f + expf(-x));
}

// ---------------------------------------------------------------------------
// K1: fused score + 3x3 NMS + per-block aggregation + global score histogram.
// key = (score_bits<<32) | ~idx  -> unsigned desc == (score desc, idx asc).
// ---------------------------------------------------------------------------
__global__ __launch_bounds__(256)
void score_nms_kernel(const float* __restrict__ route,
                      const float* __restrict__ unc,
                      u64* __restrict__ cand,
                      int* __restrict__ cnt,
                      unsigned* __restrict__ hist) {
    const int b  = blockIdx.z;
    const int bx = blockIdx.x * TW;
    const int by = blockIdx.y * TH;

    __shared__ float sc[TH + 2][SCW];
    __shared__ u64 lcand[LCAP];
    __shared__ int lcnt;
    __shared__ int gbase;

    const int tid  = threadIdx.x;
    const int lane = tid & 63;
    if (tid == 0) lcnt = 0;

    const float* rB = route + (size_t)b * IMH * IMW;
    const float* uB = unc   + (size_t)b * IMH * IMW;

    // Interior fill: 34 rows x 16 float4 (cols bx..bx+63, aligned)
    for (int i = tid; i < 34 * 16; i += 256) {
        const int row = i >> 4, c4 = i & 15;
        const int gy = by + row - 1;
        float4 s4;
        if (gy >= 0 && gy < IMH) {
            const float4 r4 = *(const float4*)(rB + (size_t)gy * IMW + bx + c4 * 4);
            const float4 u4 = *(const float4*)(uB + (size_t)gy * IMW + bx + c4 * 4);
            float sg;
            sg = sigmoidf_(r4.x); s4.x = sg * sg * (1.0f - 0.35f * sigmoidf_(u4.x));
            sg = sigmoidf_(r4.y); s4.y = sg * sg * (1.0f - 0.35f * sigmoidf_(u4.y));
            sg = sigmoidf_(r4.z); s4.z = sg * sg * (1.0f - 0.35f * sigmoidf_(u4.z));
            sg = sigmoidf_(r4.w); s4.w = sg * sg * (1.0f - 0.35f * sigmoidf_(u4.w));
        } else {
            s4 = make_float4(-INFINITY, -INFINITY, -INFINITY, -INFINITY);
        }
        *(float4*)&sc[row][4 + c4 * 4] = s4;   // 16B-aligned (row*288 + 16 + 16*c4)
    }
    // Halo columns: left (gx=bx-1 -> col 3), right (gx=bx+TW -> col 68); 34 rows each
    for (int i = tid; i < 68; i += 256) {
        const int left = (i < 34);
        const int hy = left ? i : i - 34;
        const int gy = by + hy - 1;
        const int gx = left ? bx - 1 : bx + TW;
        const int hx = left ? 3 : 4 + TW;
        float s = -INFINITY;
        if (gy >= 0 && gy < IMH && gx >= 0 && gx < IMW) {
            const float r = rB[(size_t)gy * IMW + gx];
            const float u = uB[(size_t)gy * IMW + gx];
            const float sg = sigmoidf_(r);
            s = sg * sg * (1.0f - 0.35f * sigmoidf_(u));
        }
        sc[hy][hx] = s;
    }
    __syncthreads();

    // NMS: thread -> column tx, rows ty0..ty0+7. s == maxpool3x3 <=> s >= max9
    const int tx  = tid & 63;
    const int ty0 = (tid >> 6) * 8;

    float cm[11];
    #pragma unroll
    for (int r = 0; r < 11; ++r) {
        const int y = ty0 + r;
        cm[r] = fmaxf(fmaxf(sc[y][3 + tx], sc[y][4 + tx]), sc[y][5 + tx]);
    }
    #pragma unroll
    for (int r = 0; r < 8; ++r) {
        const float s  = sc[ty0 + r + 1][4 + tx];
        const float m9 = fmaxf(fmaxf(cm[r], cm[r + 1]), cm[r + 2]);
        const bool pred = (s >= m9);
        u64 key = 0;
        if (pred) {
            const unsigned idx = (unsigned)((by + ty0 + r) * IMW + (bx + tx));
            key = ((u64)__float_as_uint(s) << 32) | (unsigned)(~idx);
        }
        // wave-aggregated LDS append
        const u64 mb = __ballot(pred);
        if (mb) {
            const int leader  = __ffsll(mb) - 1;
            const int wcount  = __popcll(mb);
            const int prefix  = __popcll(mb & ((lane == 63) ? ~0ull >> 1
                                               : ((1ull << lane) - 1)));
            int wbase = 0;
            if (lane == leader) wbase = atomicAdd(&lcnt, wcount);
            wbase = __shfl(wbase, leader, 64);
            if (pred) {
                const int pos = wbase + prefix;
                if (pos < LCAP) lcand[pos] = key;
            }
        }
    }
    __syncthreads();

    const int m = (lcnt < LCAP) ? lcnt : LCAP;
    if (tid == 0) gbase = atomicAdd(&cnt[b], m);
    __syncthreads();
    const int base = gbase;
    for (int i = tid; i < m; i += 256) {
        const int p = base + i;
        if (p < CAP) {
            const u64 k = lcand[i];
            cand[(size_t)b * CAP + p] = k;
            atomicAdd(&hist[((unsigned)b << 12) + (unsigned)(k >> 52)], 1u);
        }
    }
}

// ---------------------------------------------------------------------------
// K2: 8 blocks per image. Each block redundantly derives the exact threshold
// bin from the histogram, then compacts its slice (bin >= bstar) into surv.
// ---------------------------------------------------------------------------
__global__ __launch_bounds__(256)
void compact_kernel(const u64* __restrict__ cand,
                    const int* __restrict__ cnt,
                    const unsigned* __restrict__ hist,
                    u64* __restrict__ surv,
                    int* __restrict__ scnt) {
    const int b   = blockIdx.y;
    const int tid = threadIdx.x;
    const int lane = tid & 63;

    int n = cnt[b];
    if (n > CAP) n = CAP;

    __shared__ unsigned sA[256];
    __shared__ unsigned csS[256];
    __shared__ int bstarS;

    // chunk sums: thread t owns bins [16t, 16t+16)
    unsigned cs = 0;
    const unsigned* hb = hist + ((unsigned)b << 12);
    #pragma unroll
    for (int j = 0; j < 16; ++j) cs += hb[tid * 16 + j];
    csS[tid] = cs;
    sA[tid]  = cs;
    __syncthreads();
    // inclusive suffix sum over chunks (higher chunk = higher score)
    for (int off = 1; off < 256; off <<= 1) {
        const unsigned v = sA[tid] + ((tid + off < 256) ? sA[tid + off] : 0u);
        __syncthreads();
        sA[tid] = v;
        __syncthreads();
    }
    const unsigned total = sA[0];
    if (tid == 0) bstarS = 0;
    __syncthreads();
    if (total > (unsigned)KMAX) {
        const unsigned incl = sA[tid];
        const unsigned excl = incl - csS[tid];   // keys in chunks strictly above
        if (excl < (unsigned)KMAX && incl >= (unsigned)KMAX) {
            unsigned acc = excl;
            int bbin = tid * 16 + 15;
            for (; bbin >= tid * 16; --bbin) {
                const unsigned h = hb[bbin];
                if (acc + h >= (unsigned)KMAX) break;
                acc += h;
            }
            bstarS = bbin;
        }
    }
    __syncthreads();
    const unsigned bstar = (unsigned)bstarS;

    // compact slice
    const u64* cb = cand + (size_t)b * CAP;
    for (int i = blockIdx.x * 256 + tid; i < n; i += 8 * 256) {
        const u64 k = cb[i];
        const bool pred = ((unsigned)(k >> 52) >= bstar);
        const u64 mb = __ballot(pred);
        if (mb) {
            const int leader = __ffsll(mb) - 1;
            const int wcount = __popcll(mb);
            const int prefix = __popcll(mb & ((lane == 63) ? ~0ull >> 1
                                              : ((1ull << lane) - 1)));
            int wbase = 0;
            if (lane == leader) wbase = atomicAdd(&scnt[b], wcount);
            wbase = __shfl(wbase, leader, 64);
            if (pred) {
                const int pos = wbase + prefix;
                if (pos < SURV_CAP) surv[(size_t)b * SURV_CAP + pos] = k;
            }
        }
    }
}

// ---------------------------------------------------------------------------
// K3: 1 block per image. Exact 256th key via 16-nibble radix-select over the
// LDS-resident survivors, collect, bitonic sort desc, ROI epilogue.
// ---------------------------------------------------------------------------
__global__ __launch_bounds__(256)
void finalize_kernel(const u64* __restrict__ surv,
                     const int* __restrict__ scnt,
                     const float* __restrict__ scale,
                     const float* __restrict__ unc,
                     const int* __restrict__ imh,
                     const int* __restrict__ imw,
                     float* __restrict__ rois,
                     float* __restrict__ scoresOut,
                     float* __restrict__ validOut) {
    const int b   = blockIdx.x;
    const int tid = threadIdx.x;

    int ns = scnt[b];
    if (ns > SURV_CAP) ns = SURV_CAP;

    __shared__ u64 skeys[SURV_CAP];
    __shared__ u64 sel[KMAX];
    __shared__ unsigned h2[16];
    __shared__ u64 prefS;
    __shared__ int rem2S;
    __shared__ int c2;

    for (int i = tid; i < ns; i += 256)
        skeys[i] = surv[(size_t)b * SURV_CAP + i];
    sel[tid] = 0ull;
    if (tid == 0) c2 = 0;
    __syncthreads();

    u64 T = 0;
    if (ns > KMAX) {
        if (tid == 0) { prefS = 0; rem2S = KMAX; }
        __syncthreads();
        for (int p = 15; p >= 0; --p) {
            if (tid < 16) h2[tid] = 0;
            __syncthreads();
            const u64 pre = prefS;
            for (int i = tid; i < ns; i += 256) {
                const u64 k = skeys[i];
                const bool ok = (p == 15) || ((k >> ((p + 1) * 4)) == pre);
                if (ok) atomicAdd(&h2[(unsigned)(k >> (p * 4)) & 15u], 1u);
            }
            __syncthreads();
            if (tid == 0) {
                int rem = rem2S;
                int v;
                for (v = 15; v >= 0; --v) {
                    const int hv = (int)h2[v];
                    if (rem <= hv) break;
                    rem -= hv;
                }
                if (v < 0) v = 0;
                prefS = (pre << 4) | (unsigned)v;
                rem2S = rem;
            }
            __syncthreads();
        }
        T = prefS;
    }

    for (int i = tid; i < ns; i += 256) {
        const u64 k = skeys[i];
        if (k >= T) {
            const int p = atomicAdd(&c2, 1);
            if (p < KMAX) sel[p] = k;
        }
    }
    __syncthreads();

    // bitonic sort descending (keys unique; zeros sink)
    for (int kk = 2; kk <= KMAX; kk <<= 1) {
        for (int j = kk >> 1; j > 0; j >>= 1) {
            const int ixj = tid ^ j;
            if (ixj > tid) {
                const u64 a  = sel[tid];
                const u64 bb = sel[ixj];
                const bool desc = ((tid & kk) == 0);
                if (desc ? (a < bb) : (a > bb)) {
                    sel[tid] = bb;
                    sel[ixj] = a;
                }
            }
            __syncthreads();
        }
    }

    // epilogue
    const u64 k = sel[tid];
    const float value = __uint_as_float((unsigned)(k >> 32));
    const bool valid  = (k != 0ull) && (value > 0.0f);

    float r0 = 0.f, r1 = 0.f, r2 = 0.f, r3 = 0.f, r4 = 0.f, sv = 0.f, vv = 0.f;
    if (valid) {
        const unsigned idx = ~(unsigned)(k & 0xFFFFFFFFull);
        const int y = (int)(idx / IMW);
        const int x = (int)(idx % IMW);
        const float cx = ((float)x + 0.5f) * 4.0f;
        const float cy = ((float)y + 0.5f) * 4.0f;
        const float sg = scale[(size_t)b * IMH * IMW + idx];
        const float uu = unc[(size_t)b * IMH * IMW + idx];
        const float su = sigmoidf_(uu);
        float side = 32.0f + sigmoidf_(sg) * (512.0f - 32.0f);
        side = side * (1.0f + 0.25f * su);
        const float half = side * 0.5f;
        const float fw = (float)imw[0];
        const float fh = (float)imh[0];
        r0 = (float)b;
        r1 = fminf(fmaxf(cx - half, 0.0f), fw - 1.0f);
        r2 = fminf(fmaxf(cy - half, 0.0f), fh - 1.0f);
        r3 = fminf(fmaxf(cx + half, 1.0f), fw);
        r4 = fminf(fmaxf(cy + half, 1.0f), fh);
        sv = value;
        vv = 1.0f;
    }
    float* roiP = rois + ((size_t)b * KMAX + tid) * 5;
    roiP[0] = r0; roiP[1] = r1; roiP[2] = r2; roiP[3] = r3; roiP[4] = r4;
    scoresOut[b * KMAX + tid] = sv;
    validOut[b * KMAX + tid]  = vv;
}

extern "C" void kernel_launch(void* const* d_in, const int* in_sizes, int n_in,
                              void* d_out, int out_size, void* d_ws, size_t ws_size,
                              hipStream_t stream) {
    const float* route = (const float*)d_in[0];
    const float* scale = (const float*)d_in[1];
    const float* unc   = (const float*)d_in[2];
    const int*   imh   = (const int*)d_in[3];
    const int*   imw   = (const int*)d_in[4];

    // ws layout (15.2 MB total):
    // [cand 12.58MB][cnt 128B][scnt 128B][hist 512KB][surv 2MB]
    char* ws = (char*)d_ws;
    u64*      cand = (u64*)ws;
    size_t    off  = (size_t)BATCH * CAP * sizeof(u64);
    int*      cnt  = (int*)(ws + off);
    int*      scnt = (int*)(ws + off + 128);
    unsigned* hist = (unsigned*)(ws + off + 256);
    u64*      surv = (u64*)(ws + off + 256 + (size_t)BATCH * NB * sizeof(unsigned));

    float* rois      = (float*)d_out;                       // [B, 256, 5]
    float* scoresOut = rois + (size_t)BATCH * KMAX * 5;     // [B, 256]
    float* validOut  = scoresOut + (size_t)BATCH * KMAX;    // [B, 256]

    // one memset covers cnt + scnt + hist (contiguous)
    hipMemsetAsync(cnt, 0, 256 + (size_t)BATCH * NB * sizeof(unsigned), stream);

    dim3 grid1(IMW / TW, IMH / TH, BATCH);
    score_nms_kernel<<<grid1, 256, 0, stream>>>(route, unc, cand, cnt, hist);

    dim3 grid2(8, BATCH);
    compact_kernel<<<grid2, 256, 0, stream>>>(cand, cnt, hist, surv, scnt);

    finalize_kernel<<<BATCH, 256, 0, stream>>>(surv, scnt, scale, unc,
                                               imh, imw, rois, scoresOut, validOut);
}

// Round 4
// 142.231 us; speedup vs baseline: 2.7226x; 2.7226x over previous
//
#include <hip/hip_runtime.h>
#include <cstdint>
#include <cstddef>

#define BATCH 32
#define IMH 512
#define IMW 512
#define KMAX 256
#define CAP 36864        // per-image candidate capacity (expected ~29.3k)
#define NB 4096          // histogram bins: key bits [63:52] = sign|exp|3-mantissa
#define NSLICE 8
#define SURV_LDS 6144    // K3 LDS survivor capacity (expected ~300-600)

// K1 tiling: 64x32 pixels per 256-thread block
#define TW 64
#define TH 32
#define LCAP 1024
#define SCW 72           // LDS row stride: halo-left col 3, interior 4..67, halo-right 68

typedef unsigned long long u64;

__device__ __forceinline__ float sigmoidf_(float x) {
    return 1.0f / (1.0f + expf(-x));
}

// ---------------------------------------------------------------------------
// K1: fused score + 3x3 NMS + per-block aggregation. ONE global atomic/block.
// key = (score_bits<<32) | ~idx  -> unsigned desc == (score desc, idx asc),
// matching lax.top_k's stable tie-break.
// ---------------------------------------------------------------------------
__global__ __launch_bounds__(256)
void score_nms_kernel(const float* __restrict__ route,
                      const float* __restrict__ unc,
                      u64* __restrict__ cand,
                      int* __restrict__ cnt) {
    const int b  = blockIdx.z;
    const int bx = blockIdx.x * TW;
    const int by = blockIdx.y * TH;

    __shared__ float sc[TH + 2][SCW];
    __shared__ u64 lcand[LCAP];
    __shared__ int lcnt;
    __shared__ int gbase;

    const int tid  = threadIdx.x;
    const int lane = tid & 63;
    if (tid == 0) lcnt = 0;

    const float* rB = route + (size_t)b * IMH * IMW;
    const float* uB = unc   + (size_t)b * IMH * IMW;

    // Interior fill: 34 rows x 16 float4 (cols bx..bx+63, 16B-aligned)
    for (int i = tid; i < 34 * 16; i += 256) {
        const int row = i >> 4, c4 = i & 15;
        const int gy = by + row - 1;
        float4 s4;
        if (gy >= 0 && gy < IMH) {
            const float4 r4 = *(const float4*)(rB + (size_t)gy * IMW + bx + c4 * 4);
            const float4 u4 = *(const float4*)(uB + (size_t)gy * IMW + bx + c4 * 4);
            float sg;
            sg = sigmoidf_(r4.x); s4.x = sg * sg * (1.0f - 0.35f * sigmoidf_(u4.x));
            sg = sigmoidf_(r4.y); s4.y = sg * sg * (1.0f - 0.35f * sigmoidf_(u4.y));
            sg = sigmoidf_(r4.z); s4.z = sg * sg * (1.0f - 0.35f * sigmoidf_(u4.z));
            sg = sigmoidf_(r4.w); s4.w = sg * sg * (1.0f - 0.35f * sigmoidf_(u4.w));
        } else {
            s4 = make_float4(-INFINITY, -INFINITY, -INFINITY, -INFINITY);
        }
        *(float4*)&sc[row][4 + c4 * 4] = s4;
    }
    // Halo columns: left (gx=bx-1 -> col 3), right (gx=bx+TW -> col 68)
    for (int i = tid; i < 68; i += 256) {
        const int left = (i < 34);
        const int hy = left ? i : i - 34;
        const int gy = by + hy - 1;
        const int gx = left ? bx - 1 : bx + TW;
        const int hx = left ? 3 : 4 + TW;
        float s = -INFINITY;
        if (gy >= 0 && gy < IMH && gx >= 0 && gx < IMW) {
            const float r = rB[(size_t)gy * IMW + gx];
            const float u = uB[(size_t)gy * IMW + gx];
            const float sg = sigmoidf_(r);
            s = sg * sg * (1.0f - 0.35f * sigmoidf_(u));
        }
        sc[hy][hx] = s;
    }
    __syncthreads();

    // NMS: thread -> column tx, rows ty0..ty0+7. s == maxpool3x3 <=> s >= max9
    const int tx  = tid & 63;
    const int ty0 = (tid >> 6) * 8;

    float cm[11];
    #pragma unroll
    for (int r = 0; r < 11; ++r) {
        const int y = ty0 + r;
        cm[r] = fmaxf(fmaxf(sc[y][3 + tx], sc[y][4 + tx]), sc[y][5 + tx]);
    }
    #pragma unroll
    for (int r = 0; r < 8; ++r) {
        const float s  = sc[ty0 + r + 1][4 + tx];
        const float m9 = fmaxf(fmaxf(cm[r], cm[r + 1]), cm[r + 2]);
        const bool pred = (s >= m9);
        u64 key = 0;
        if (pred) {
            const unsigned idx = (unsigned)((by + ty0 + r) * IMW + (bx + tx));
            key = ((u64)__float_as_uint(s) << 32) | (unsigned)(~idx);
        }
        const u64 mb = __ballot(pred);
        if (mb) {
            const int leader = __ffsll(mb) - 1;
            const int wcount = __popcll(mb);
            const int prefix = __popcll(mb & ((1ull << lane) - 1));
            int wbase = 0;
            if (lane == leader) wbase = atomicAdd(&lcnt, wcount);
            wbase = __shfl(wbase, leader, 64);
            if (pred) {
                const int pos = wbase + prefix;
                if (pos < LCAP) lcand[pos] = key;
            }
        }
    }
    __syncthreads();

    const int m = (lcnt < LCAP) ? lcnt : LCAP;
    if (tid == 0) gbase = atomicAdd(&cnt[b], m);
    __syncthreads();
    const int base = gbase;
    for (int i = tid; i < m; i += 256) {
        const int p = base + i;
        if (p < CAP) cand[(size_t)b * CAP + p] = lcand[i];
    }
}

// ---------------------------------------------------------------------------
// K2: (slice, image) blocks. Block-private LDS histogram of its strided slice,
// then plain stores to slicehist[b][slice][.] — zero global atomics.
// ---------------------------------------------------------------------------
__global__ __launch_bounds__(256)
void slice_hist_kernel(const u64* __restrict__ cand,
                       const int* __restrict__ cnt,
                       unsigned* __restrict__ slicehist) {
    const int slice = blockIdx.x;
    const int b     = blockIdx.y;
    const int tid   = threadIdx.x;

    __shared__ unsigned hist[NB];
    for (int i = tid; i < NB; i += 256) hist[i] = 0;
    __syncthreads();

    int n = cnt[b];
    if (n > CAP) n = CAP;
    const u64* cb = cand + (size_t)b * CAP;
    for (int i = slice * 256 + tid; i < n; i += NSLICE * 256)
        atomicAdd(&hist[(unsigned)(cb[i] >> 52)], 1u);
    __syncthreads();

    unsigned* out = slicehist + (((size_t)b * NSLICE + slice) << 12);
    for (int i = tid; i < NB; i += 256) out[i] = hist[i];
}

// ---------------------------------------------------------------------------
// K3: 1 block/image. Sum slice hists -> exact threshold bin; single scan of
// cand keeps bin >= bstar in LDS; nibble radix-select -> exact 256th key;
// collect, bitonic sort desc, ROI epilogue.
// ---------------------------------------------------------------------------
__global__ __launch_bounds__(256)
void finalize_kernel(const u64* __restrict__ cand,
                     const int* __restrict__ cnt,
                     const unsigned* __restrict__ slicehist,
                     const float* __restrict__ scale,
                     const float* __restrict__ unc,
                     const int* __restrict__ imh,
                     const int* __restrict__ imw,
                     float* __restrict__ rois,
                     float* __restrict__ scoresOut,
                     float* __restrict__ validOut) {
    const int b   = blockIdx.x;
    const int tid = threadIdx.x;

    __shared__ u64 buf64[SURV_LDS];          // phase A: tot hist u32[4096]; phase B: survivors
    __shared__ unsigned sA[256], csS[256];
    __shared__ u64 sel[KMAX];
    __shared__ unsigned h2[16];
    __shared__ u64 prefS;
    __shared__ int bstarS, scntS, rem2S, c2S;

    unsigned* tot = (unsigned*)buf64;

    int n = cnt[b];
    if (n > CAP) n = CAP;

    // ---- phase A: total histogram + threshold bin ----
    const unsigned* shB = slicehist + (((size_t)b * NSLICE) << 12);
    for (int i = tid; i < NB; i += 256) {
        unsigned t = 0;
        #pragma unroll
        for (int s = 0; s < NSLICE; ++s) t += shB[(s << 12) + i];
        tot[i] = t;
    }
    if (tid == 0) { bstarS = 0; scntS = 0; c2S = 0; }
    sel[tid] = 0ull;
    __syncthreads();

    unsigned cs = 0;
    #pragma unroll
    for (int j = 0; j < 16; ++j) cs += tot[tid * 16 + j];
    csS[tid] = cs;
    sA[tid]  = cs;
    __syncthreads();
    for (int off = 1; off < 256; off <<= 1) {
        const unsigned v = sA[tid] + ((tid + off < 256) ? sA[tid + off] : 0u);
        __syncthreads();
        sA[tid] = v;
        __syncthreads();
    }
    const unsigned total = sA[0];
    if (total > (unsigned)KMAX) {
        const unsigned incl = sA[tid];
        const unsigned excl = incl - csS[tid];
        if (excl < (unsigned)KMAX && incl >= (unsigned)KMAX) {
            unsigned acc = excl;
            int bbin = tid * 16 + 15;
            for (; bbin > tid * 16; --bbin) {
                const unsigned h = tot[bbin];
                if (acc + h >= (unsigned)KMAX) break;
                acc += h;
            }
            bstarS = bbin;
        }
    }
    __syncthreads();
    const unsigned bstar = (unsigned)bstarS;
    __syncthreads();     // all reads of tot[] done before buf64 reuse

    // ---- phase B: compact survivors (bin >= bstar) into LDS ----
    const u64* cb = cand + (size_t)b * CAP;
    for (int i = tid; i < n; i += 256) {
        const u64 k = cb[i];
        if ((unsigned)(k >> 52) >= bstar) {
            const int p = atomicAdd(&scntS, 1);
            if (p < SURV_LDS) buf64[p] = k;
        }
    }
    __syncthreads();
    int ns = scntS;
    if (ns > SURV_LDS) ns = SURV_LDS;

    // ---- exact 256th key via nibble radix-select ----
    u64 T = 0;
    if (ns > KMAX) {
        if (tid == 0) { prefS = 0; rem2S = KMAX; }
        __syncthreads();
        for (int p = 15; p >= 0; --p) {
            if (tid < 16) h2[tid] = 0;
            __syncthreads();
            const u64 pre = prefS;
            for (int i = tid; i < ns; i += 256) {
                const u64 k = buf64[i];
                const bool ok = (p == 15) || ((k >> ((p + 1) * 4)) == pre);
                if (ok) atomicAdd(&h2[(unsigned)(k >> (p * 4)) & 15u], 1u);
            }
            __syncthreads();
            if (tid == 0) {
                int rem = rem2S;
                int v;
                for (v = 15; v >= 0; --v) {
                    const int hv = (int)h2[v];
                    if (rem <= hv) break;
                    rem -= hv;
                }
                if (v < 0) v = 0;
                prefS = (pre << 4) | (unsigned)v;
                rem2S = rem;
            }
            __syncthreads();
        }
        T = prefS;
    }

    for (int i = tid; i < ns; i += 256) {
        const u64 k = buf64[i];
        if (k >= T && k != 0ull) {
            const int p = atomicAdd(&c2S, 1);
            if (p < KMAX) sel[p] = k;
        }
    }
    __syncthreads();

    // ---- bitonic sort descending (keys unique; zeros sink) ----
    for (int kk = 2; kk <= KMAX; kk <<= 1) {
        for (int j = kk >> 1; j > 0; j >>= 1) {
            const int ixj = tid ^ j;
            if (ixj > tid) {
                const u64 a  = sel[tid];
                const u64 bb = sel[ixj];
                const bool desc = ((tid & kk) == 0);
                if (desc ? (a < bb) : (a > bb)) {
                    sel[tid] = bb;
                    sel[ixj] = a;
                }
            }
            __syncthreads();
        }
    }

    // ---- epilogue ----
    const u64 k = sel[tid];
    const float value = __uint_as_float((unsigned)(k >> 32));
    const bool valid  = (k != 0ull) && (value > 0.0f);

    float r0 = 0.f, r1 = 0.f, r2 = 0.f, r3 = 0.f, r4 = 0.f, sv = 0.f, vv = 0.f;
    if (valid) {
        const unsigned idx = ~(unsigned)(k & 0xFFFFFFFFull);
        const int y = (int)(idx / IMW);
        const int x = (int)(idx % IMW);
        const float cx = ((float)x + 0.5f) * 4.0f;
        const float cy = ((float)y + 0.5f) * 4.0f;
        const float sg = scale[(size_t)b * IMH * IMW + idx];
        const float uu = unc[(size_t)b * IMH * IMW + idx];
        const float su = sigmoidf_(uu);
        float side = 32.0f + sigmoidf_(sg) * (512.0f - 32.0f);
        side = side * (1.0f + 0.25f * su);
        const float half = side * 0.5f;
        const float fw = (float)imw[0];
        const float fh = (float)imh[0];
        r0 = (float)b;
        r1 = fminf(fmaxf(cx - half, 0.0f), fw - 1.0f);
        r2 = fminf(fmaxf(cy - half, 0.0f), fh - 1.0f);
        r3 = fminf(fmaxf(cx + half, 1.0f), fw);
        r4 = fminf(fmaxf(cy + half, 1.0f), fh);
        sv = value;
        vv = 1.0f;
    }
    float* roiP = rois + ((size_t)b * KMAX + tid) * 5;
    roiP[0] = r0; roiP[1] = r1; roiP[2] = r2; roiP[3] = r3; roiP[4] = r4;
    scoresOut[b * KMAX + tid] = sv;
    validOut[b * KMAX + tid]  = vv;
}

extern "C" void kernel_launch(void* const* d_in, const int* in_sizes, int n_in,
                              void* d_out, int out_size, void* d_ws, size_t ws_size,
                              hipStream_t stream) {
    const float* route = (const float*)d_in[0];
    const float* scale = (const float*)d_in[1];
    const float* unc   = (const float*)d_in[2];
    const int*   imh   = (const int*)d_in[3];
    const int*   imw   = (const int*)d_in[4];

    // ws layout (~13.6 MB): [cand 9.44MB][cnt 256B][slicehist 4MB]
    char* ws = (char*)d_ws;
    u64*      cand = (u64*)ws;
    size_t    off  = (size_t)BATCH * CAP * sizeof(u64);
    int*      cnt  = (int*)(ws + off);
    unsigned* slicehist = (unsigned*)(ws + off + 256);

    float* rois      = (float*)d_out;                       // [B, 256, 5]
    float* scoresOut = rois + (size_t)BATCH * KMAX * 5;     // [B, 256]
    float* validOut  = scoresOut + (size_t)BATCH * KMAX;    // [B, 256]

    hipMemsetAsync(cnt, 0, BATCH * sizeof(int), stream);

    dim3 grid1(IMW / TW, IMH / TH, BATCH);
    score_nms_kernel<<<grid1, 256, 0, stream>>>(route, unc, cand, cnt);

    dim3 grid2(NSLICE, BATCH);
    slice_hist_kernel<<<grid2, 256, 0, stream>>>(cand, cnt, slicehist);

    finalize_kernel<<<BATCH, 256, 0, stream>>>(cand, cnt, slicehist, scale, unc,
                                               imh, imw, rois, scoresOut, validOut);
}

// Round 5
// 109.031 us; speedup vs baseline: 3.5517x; 1.3045x over previous
//
#include <hip/hip_runtime.h>
#include <cstdint>
#include <cstddef>

#define BATCH 32
#define IMH 512
#define IMW 512
#define KMAX 256
#define CAP 36864        // per-image candidate capacity (expected ~29.3k)
#define NB 4096          // histogram bins: key bits [63:52] = sign|exp|3-mantissa
#define NSLICE 8
#define SURV_CAP 6144    // per-image survivor capacity (expected ~300-600)
#define SKEYS 4096       // finalize LDS cap for bin* keys
#define LBUF 1024        // compact per-block LDS survivor buffer

// K1 tiling: 64x32 pixels per 256-thread block
#define TW 64
#define TH 32
#define LCAP 1024
#define SCW 72           // LDS row stride: halo-left col 3, interior 4..67, halo-right 68

typedef unsigned long long u64;

__device__ __forceinline__ float sigmoidf_(float x) {
    return 1.0f / (1.0f + expf(-x));
}

// ---------------------------------------------------------------------------
// K1: fused score + 3x3 NMS + per-block aggregation. ONE global atomic/block.
// key = (score_bits<<32) | ~idx  -> unsigned desc == (score desc, idx asc),
// matching lax.top_k's stable tie-break.
// ---------------------------------------------------------------------------
__global__ __launch_bounds__(256)
void score_nms_kernel(const float* __restrict__ route,
                      const float* __restrict__ unc,
                      u64* __restrict__ cand,
                      int* __restrict__ cnt) {
    const int b  = blockIdx.z;
    const int bx = blockIdx.x * TW;
    const int by = blockIdx.y * TH;

    __shared__ float sc[TH + 2][SCW];
    __shared__ u64 lcand[LCAP];
    __shared__ int lcnt;
    __shared__ int gbase;

    const int tid  = threadIdx.x;
    const int lane = tid & 63;
    if (tid == 0) lcnt = 0;

    const float* rB = route + (size_t)b * IMH * IMW;
    const float* uB = unc   + (size_t)b * IMH * IMW;

    // Interior fill: 34 rows x 16 float4 (cols bx..bx+63, 16B-aligned)
    for (int i = tid; i < 34 * 16; i += 256) {
        const int row = i >> 4, c4 = i & 15;
        const int gy = by + row - 1;
        float4 s4;
        if (gy >= 0 && gy < IMH) {
            const float4 r4 = *(const float4*)(rB + (size_t)gy * IMW + bx + c4 * 4);
            const float4 u4 = *(const float4*)(uB + (size_t)gy * IMW + bx + c4 * 4);
            float sg;
            sg = sigmoidf_(r4.x); s4.x = sg * sg * (1.0f - 0.35f * sigmoidf_(u4.x));
            sg = sigmoidf_(r4.y); s4.y = sg * sg * (1.0f - 0.35f * sigmoidf_(u4.y));
            sg = sigmoidf_(r4.z); s4.z = sg * sg * (1.0f - 0.35f * sigmoidf_(u4.z));
            sg = sigmoidf_(r4.w); s4.w = sg * sg * (1.0f - 0.35f * sigmoidf_(u4.w));
        } else {
            s4 = make_float4(-INFINITY, -INFINITY, -INFINITY, -INFINITY);
        }
        *(float4*)&sc[row][4 + c4 * 4] = s4;
    }
    // Halo columns: left (gx=bx-1 -> col 3), right (gx=bx+TW -> col 68)
    for (int i = tid; i < 68; i += 256) {
        const int left = (i < 34);
        const int hy = left ? i : i - 34;
        const int gy = by + hy - 1;
        const int gx = left ? bx - 1 : bx + TW;
        const int hx = left ? 3 : 4 + TW;
        float s = -INFINITY;
        if (gy >= 0 && gy < IMH && gx >= 0 && gx < IMW) {
            const float r = rB[(size_t)gy * IMW + gx];
            const float u = uB[(size_t)gy * IMW + gx];
            const float sg = sigmoidf_(r);
            s = sg * sg * (1.0f - 0.35f * sigmoidf_(u));
        }
        sc[hy][hx] = s;
    }
    __syncthreads();

    // NMS: thread -> column tx, rows ty0..ty0+7. s == maxpool3x3 <=> s >= max9
    const int tx  = tid & 63;
    const int ty0 = (tid >> 6) * 8;

    float cm[11];
    #pragma unroll
    for (int r = 0; r < 11; ++r) {
        const int y = ty0 + r;
        cm[r] = fmaxf(fmaxf(sc[y][3 + tx], sc[y][4 + tx]), sc[y][5 + tx]);
    }
    #pragma unroll
    for (int r = 0; r < 8; ++r) {
        const float s  = sc[ty0 + r + 1][4 + tx];
        const float m9 = fmaxf(fmaxf(cm[r], cm[r + 1]), cm[r + 2]);
        const bool pred = (s >= m9);
        u64 key = 0;
        if (pred) {
            const unsigned idx = (unsigned)((by + ty0 + r) * IMW + (bx + tx));
            key = ((u64)__float_as_uint(s) << 32) | (unsigned)(~idx);
        }
        const u64 mb = __ballot(pred);
        if (mb) {
            const int leader = __ffsll(mb) - 1;
            const int wcount = __popcll(mb);
            const int prefix = __popcll(mb & ((1ull << lane) - 1));
            int wbase = 0;
            if (lane == leader) wbase = atomicAdd(&lcnt, wcount);
            wbase = __shfl(wbase, leader, 64);
            if (pred) {
                const int pos = wbase + prefix;
                if (pos < LCAP) lcand[pos] = key;
            }
        }
    }
    __syncthreads();

    const int m = (lcnt < LCAP) ? lcnt : LCAP;
    if (tid == 0) gbase = atomicAdd(&cnt[b], m);
    __syncthreads();
    const int base = gbase;
    for (int i = tid; i < m; i += 256) {
        const int p = base + i;
        if (p < CAP) cand[(size_t)b * CAP + p] = lcand[i];
    }
}

// ---------------------------------------------------------------------------
// K2: (slice, image) blocks. Block-private LDS histogram of its strided slice,
// then plain stores to slicehist[b][slice][.] — zero global atomics.
// ---------------------------------------------------------------------------
__global__ __launch_bounds__(256)
void slice_hist_kernel(const u64* __restrict__ cand,
                       const int* __restrict__ cnt,
                       unsigned* __restrict__ slicehist) {
    const int slice = blockIdx.x;
    const int b     = blockIdx.y;
    const int tid   = threadIdx.x;

    __shared__ unsigned hist[NB];
    for (int i = tid; i < NB; i += 256) hist[i] = 0;
    __syncthreads();

    int n = cnt[b];
    if (n > CAP) n = CAP;
    const u64* cb = cand + (size_t)b * CAP;
    for (int i = slice * 256 + tid; i < n; i += NSLICE * 256)
        atomicAdd(&hist[(unsigned)(cb[i] >> 52)], 1u);
    __syncthreads();

    unsigned* out = slicehist + (((size_t)b * NSLICE + slice) << 12);
    for (int i = tid; i < NB; i += 256) out[i] = hist[i];
}

// ---------------------------------------------------------------------------
// K3: (slice, image) blocks. Each block re-derives the exact threshold bin
// bstar + above-count from slicehist (pure reads), compacts its slice
// (bin >= bstar) into an LDS buffer, flushes with ONE global atomic/block.
// Block (0, b) also publishes {bstar, above} to meta[b].
// ---------------------------------------------------------------------------
__global__ __launch_bounds__(256)
void compact_kernel(const u64* __restrict__ cand,
                    const int* __restrict__ cnt,
                    const unsigned* __restrict__ slicehist,
                    u64* __restrict__ surv,
                    int* __restrict__ scnt,
                    int* __restrict__ meta) {
    const int slice = blockIdx.x;
    const int b     = blockIdx.y;
    const int tid   = threadIdx.x;
    const int lane  = tid & 63;

    __shared__ unsigned tot[NB];          // 16 KB
    __shared__ unsigned sA[256], csS[256];
    __shared__ int bstarS, aboveS;
    __shared__ u64 lbuf[LBUF];
    __shared__ int lcnt2, gbase2;

    int n = cnt[b];
    if (n > CAP) n = CAP;

    const unsigned* shB = slicehist + (((size_t)b * NSLICE) << 12);
    for (int i = tid; i < NB; i += 256) {
        unsigned t = 0;
        #pragma unroll
        for (int s = 0; s < NSLICE; ++s) t += shB[(s << 12) + i];
        tot[i] = t;
    }
    if (tid == 0) { bstarS = 0; aboveS = 0; lcnt2 = 0; }
    __syncthreads();

    unsigned cs = 0;
    #pragma unroll
    for (int j = 0; j < 16; ++j) cs += tot[tid * 16 + j];
    csS[tid] = cs;
    sA[tid]  = cs;
    __syncthreads();
    for (int off = 1; off < 256; off <<= 1) {
        const unsigned v = sA[tid] + ((tid + off < 256) ? sA[tid + off] : 0u);
        __syncthreads();
        sA[tid] = v;
        __syncthreads();
    }
    const unsigned total = sA[0];
    if (total > (unsigned)KMAX) {
        const unsigned incl = sA[tid];
        const unsigned excl = incl - csS[tid];
        if (excl < (unsigned)KMAX && incl >= (unsigned)KMAX) {
            unsigned acc = excl;
            int bbin = tid * 16 + 15;
            for (; bbin > tid * 16; --bbin) {
                const unsigned h = tot[bbin];
                if (acc + h >= (unsigned)KMAX) break;
                acc += h;
            }
            bstarS = bbin;
            aboveS = (int)acc;     // keys in bins strictly above bstar (< 256)
        }
    }
    __syncthreads();
    const unsigned bstar = (unsigned)bstarS;
    if (slice == 0 && tid == 0) { meta[b * 2] = bstarS; meta[b * 2 + 1] = aboveS; }

    // compact my slice into LDS, then one global flush
    const u64* cb = cand + (size_t)b * CAP;
    for (int i = slice * 256 + tid; i < n; i += NSLICE * 256) {
        const u64 k = cb[i];
        const bool pred = ((unsigned)(k >> 52) >= bstar);
        const u64 mb = __ballot(pred);
        if (mb) {
            const int leader = __ffsll(mb) - 1;
            const int wcount = __popcll(mb);
            const int prefix = __popcll(mb & ((1ull << lane) - 1));
            int wb_ = 0;
            if (lane == leader) wb_ = atomicAdd(&lcnt2, wcount);
            wb_ = __shfl(wb_, leader, 64);
            if (pred) {
                const int pos = wb_ + prefix;
                if (pos < LBUF) lbuf[pos] = k;
            }
        }
    }
    __syncthreads();
    int m = lcnt2;
    if (m > LBUF) m = LBUF;
    if (tid == 0) gbase2 = atomicAdd(&scnt[b], m);
    __syncthreads();
    const int base = gbase2;
    for (int i = tid; i < m; i += 256) {
        const int p = base + i;
        if (p < SURV_CAP) surv[(size_t)b * SURV_CAP + p] = lbuf[i];
    }
}

// ---------------------------------------------------------------------------
// K4: 1 block/image. Survivors split on load: bin > bstar -> sel directly;
// bin == bstar -> skeys. Radix-select only over skeys' low 13 nibbles
// (prefix = bstar known) -> exact threshold key T; collect; bitonic; epilogue.
// ---------------------------------------------------------------------------
__global__ __launch_bounds__(256)
void finalize_kernel(const u64* __restrict__ surv,
                     const int* __restrict__ scnt,
                     const int* __restrict__ meta,
                     const float* __restrict__ scale,
                     const float* __restrict__ unc,
                     const int* __restrict__ imh,
                     const int* __restrict__ imw,
                     float* __restrict__ rois,
                     float* __restrict__ scoresOut,
                     float* __restrict__ validOut) {
    const int b   = blockIdx.x;
    const int tid = threadIdx.x;

    __shared__ u64 skeys[SKEYS];
    __shared__ u64 sel[KMAX];
    __shared__ unsigned h2[16];
    __shared__ u64 prefS;
    __shared__ int rem2S, cSel, cSk;

    int ns = scnt[b];
    if (ns > SURV_CAP) ns = SURV_CAP;
    const unsigned bstar = (unsigned)meta[b * 2];

    sel[tid] = 0ull;
    if (tid == 0) { cSel = 0; cSk = 0; }
    __syncthreads();

    const u64* sb = surv + (size_t)b * SURV_CAP;
    for (int i = tid; i < ns; i += 256) {
        const u64 k = sb[i];
        if ((unsigned)(k >> 52) > bstar) {
            const int p = atomicAdd(&cSel, 1);
            if (p < KMAX) sel[p] = k;          // above-bin keys: < 256 guaranteed
        } else {
            const int p = atomicAdd(&cSk, 1);
            if (p < SKEYS) skeys[p] = k;       // bin* keys
        }
    }
    __syncthreads();
    const int above = cSel;
    int nk = cSk;
    if (nk > SKEYS) nk = SKEYS;
    const int remk = KMAX - above;

    u64 T = 0;
    if (nk > remk) {
        if (tid == 0) { prefS = (u64)bstar; rem2S = remk; }
        __syncthreads();
        for (int p = 12; p >= 0; --p) {
            if (tid < 16) h2[tid] = 0;
            __syncthreads();
            const u64 pre = prefS;
            for (int i = tid; i < nk; i += 256) {
                const u64 k = skeys[i];
                if ((k >> ((p + 1) * 4)) == pre)
                    atomicAdd(&h2[(unsigned)(k >> (p * 4)) & 15u], 1u);
            }
            __syncthreads();
            if (tid == 0) {
                int rem = rem2S;
                int v;
                for (v = 15; v >= 0; --v) {
                    const int hv = (int)h2[v];
                    if (rem <= hv) break;
                    rem -= hv;
                }
                if (v < 0) v = 0;
                prefS = (pre << 4) | (unsigned)v;
                rem2S = rem;
            }
            __syncthreads();
        }
        T = prefS;
    }

    for (int i = tid; i < nk; i += 256) {
        const u64 k = skeys[i];
        if (k >= T) {
            const int p = atomicAdd(&cSel, 1);
            if (p < KMAX) sel[p] = k;          // exactly remk when nk > remk
        }
    }
    __syncthreads();

    // ---- bitonic sort descending (keys unique; zeros sink) ----
    for (int kk = 2; kk <= KMAX; kk <<= 1) {
        for (int j = kk >> 1; j > 0; j >>= 1) {
            const int ixj = tid ^ j;
            if (ixj > tid) {
                const u64 a  = sel[tid];
                const u64 bb = sel[ixj];
                const bool desc = ((tid & kk) == 0);
                if (desc ? (a < bb) : (a > bb)) {
                    sel[tid] = bb;
                    sel[ixj] = a;
                }
            }
            __syncthreads();
        }
    }

    // ---- epilogue ----
    const u64 k = sel[tid];
    const float value = __uint_as_float((unsigned)(k >> 32));
    const bool valid  = (k != 0ull) && (value > 0.0f);

    float r0 = 0.f, r1 = 0.f, r2 = 0.f, r3 = 0.f, r4 = 0.f, sv = 0.f, vv = 0.f;
    if (valid) {
        const unsigned idx = ~(unsigned)(k & 0xFFFFFFFFull);
        const int y = (int)(idx / IMW);
        const int x = (int)(idx % IMW);
        const float cx = ((float)x + 0.5f) * 4.0f;
        const float cy = ((float)y + 0.5f) * 4.0f;
        const float sg = scale[(size_t)b * IMH * IMW + idx];
        const float uu = unc[(size_t)b * IMH * IMW + idx];
        const float su = sigmoidf_(uu);
        float side = 32.0f + sigmoidf_(sg) * (512.0f - 32.0f);
        side = side * (1.0f + 0.25f * su);
        const float half = side * 0.5f;
        const float fw = (float)imw[0];
        const float fh = (float)imh[0];
        r0 = (float)b;
        r1 = fminf(fmaxf(cx - half, 0.0f), fw - 1.0f);
        r2 = fminf(fmaxf(cy - half, 0.0f), fh - 1.0f);
        r3 = fminf(fmaxf(cx + half, 1.0f), fw);
        r4 = fminf(fmaxf(cy + half, 1.0f), fh);
        sv = value;
        vv = 1.0f;
    }
    float* roiP = rois + ((size_t)b * KMAX + tid) * 5;
    roiP[0] = r0; roiP[1] = r1; roiP[2] = r2; roiP[3] = r3; roiP[4] = r4;
    scoresOut[b * KMAX + tid] = sv;
    validOut[b * KMAX + tid]  = vv;
}

extern "C" void kernel_launch(void* const* d_in, const int* in_sizes, int n_in,
                              void* d_out, int out_size, void* d_ws, size_t ws_size,
                              hipStream_t stream) {
    const float* route = (const float*)d_in[0];
    const float* scale = (const float*)d_in[1];
    const float* unc   = (const float*)d_in[2];
    const int*   imh   = (const int*)d_in[3];
    const int*   imw   = (const int*)d_in[4];

    // ws layout (~15.2 MB):
    // [cand 9.44MB][cnt 128B][scnt 128B][meta 256B][slicehist 4MB][surv 1.5MB]
    char* ws = (char*)d_ws;
    u64*      cand = (u64*)ws;
    size_t    off  = (size_t)BATCH * CAP * sizeof(u64);
    int*      cnt  = (int*)(ws + off);
    int*      scnt = (int*)(ws + off + 128);
    int*      meta = (int*)(ws + off + 256);
    unsigned* slicehist = (unsigned*)(ws + off + 512);
    u64*      surv = (u64*)(ws + off + 512 + (size_t)BATCH * NSLICE * NB * sizeof(unsigned));

    float* rois      = (float*)d_out;                       // [B, 256, 5]
    float* scoresOut = rois + (size_t)BATCH * KMAX * 5;     // [B, 256]
    float* validOut  = scoresOut + (size_t)BATCH * KMAX;    // [B, 256]

    hipMemsetAsync(cnt, 0, 512, stream);   // cnt + scnt + meta

    dim3 grid1(IMW / TW, IMH / TH, BATCH);
    score_nms_kernel<<<grid1, 256, 0, stream>>>(route, unc, cand, cnt);

    dim3 grid2(NSLICE, BATCH);
    slice_hist_kernel<<<grid2, 256, 0, stream>>>(cand, cnt, slicehist);
    compact_kernel<<<grid2, 256, 0, stream>>>(cand, cnt, slicehist, surv, scnt, meta);

    finalize_kernel<<<BATCH, 256, 0, stream>>>(surv, scnt, meta, scale, unc,
                                               imh, imw, rois, scoresOut, validOut);
}

// Round 6
// 106.381 us; speedup vs baseline: 3.6401x; 1.0249x over previous
//
#include <hip/hip_runtime.h>
#include <cstdint>
#include <cstddef>

#define BATCH 32
#define IMH 512
#define IMW 512
#define KMAX 256
#define CAP 36864        // per-image candidate capacity (expected ~29.3k)
#define NB 4096          // histogram bins: key bits [63:52]
#define NSLICE 8
#define SURV_CAP 8192    // per-image survivor capacity (expected ~300-3000)
#define SKEYS 6144       // finalize LDS cap for bin* keys
#define LBUF 1024        // compact per-block LDS survivor buffer

// K1 tiling: 64x32 pixels per 256-thread block
#define TW 64
#define TH 32
#define LCAP 1024
#define SCW 72           // floats/row: left halo quad 0..3, interior 4..67, right 68..71

typedef unsigned long long u64;

__device__ __forceinline__ float sigmoidf_(float x) {
    return 1.0f / (1.0f + expf(-x));
}

// ---------------------------------------------------------------------------
// K1: fused score + 3x3 NMS + per-block aggregation. ONE global atomic/block,
// ONE LDS atomic/wave. NMS reads: 1 ds_read_b128 + 2 ds_read_b32 per row.
// key = (score_bits<<32) | ~idx  -> unsigned desc == (score desc, idx asc).
// ---------------------------------------------------------------------------
__global__ __launch_bounds__(256)
void score_nms_kernel(const float* __restrict__ route,
                      const float* __restrict__ unc,
                      u64* __restrict__ cand,
                      int* __restrict__ cnt) {
    const int b  = blockIdx.z;
    const int bx = blockIdx.x * TW;
    const int by = blockIdx.y * TH;

    __shared__ float sc[TH + 2][SCW];
    __shared__ u64 lcand[LCAP];
    __shared__ int lcnt;
    __shared__ int gbase;

    const int tid  = threadIdx.x;
    const int lane = tid & 63;
    if (tid == 0) lcnt = 0;

    const float* rB = route + (size_t)b * IMH * IMW;
    const float* uB = unc   + (size_t)b * IMH * IMW;

    // Interior fill: 34 rows x 16 float4 (cols bx..bx+63, 16B-aligned)
    for (int i = tid; i < 34 * 16; i += 256) {
        const int row = i >> 4, c4 = i & 15;
        const int gy = by + row - 1;
        float4 s4;
        if (gy >= 0 && gy < IMH) {
            const float4 r4 = *(const float4*)(rB + (size_t)gy * IMW + bx + c4 * 4);
            const float4 u4 = *(const float4*)(uB + (size_t)gy * IMW + bx + c4 * 4);
            float sg;
            sg = sigmoidf_(r4.x); s4.x = sg * sg * (1.0f - 0.35f * sigmoidf_(u4.x));
            sg = sigmoidf_(r4.y); s4.y = sg * sg * (1.0f - 0.35f * sigmoidf_(u4.y));
            sg = sigmoidf_(r4.z); s4.z = sg * sg * (1.0f - 0.35f * sigmoidf_(u4.z));
            sg = sigmoidf_(r4.w); s4.w = sg * sg * (1.0f - 0.35f * sigmoidf_(u4.w));
        } else {
            s4 = make_float4(-INFINITY, -INFINITY, -INFINITY, -INFINITY);
        }
        *(float4*)&sc[row][4 + c4 * 4] = s4;
    }
    // Side halo columns: col bx-1 -> sc[.][3], col bx+64 -> sc[.][68]
    for (int i = tid; i < 68; i += 256) {
        const int left = (i < 34);
        const int hy = left ? i : i - 34;
        const int gy = by + hy - 1;
        const int gx = left ? bx - 1 : bx + TW;
        const int hx = left ? 3 : 4 + TW;
        float s = -INFINITY;
        if (gy >= 0 && gy < IMH && gx >= 0 && gx < IMW) {
            const float r = rB[(size_t)gy * IMW + gx];
            const float u = uB[(size_t)gy * IMW + gx];
            const float sg = sigmoidf_(r);
            s = sg * sg * (1.0f - 0.35f * sigmoidf_(u));
        }
        sc[hy][hx] = s;
    }
    __syncthreads();

    // NMS: thread (c, rg): cols 4c..4c+3, output tile rows t0=1+2rg, t0+1.
    const int c  = tid & 15;
    const int rg = tid >> 4;
    const int t0 = 1 + 2 * rg;

    float rm[4][4];      // center quads for rows t0-1..t0+2
    float hm[4][4];      // horizontal max3 per row
    #pragma unroll
    for (int k = 0; k < 4; ++k) {
        const int t = t0 - 1 + k;
        const float  lw = sc[t][3 + 4 * c];
        const float4 m4 = *(const float4*)&sc[t][4 + 4 * c];
        const float  rx = sc[t][8 + 4 * c];
        rm[k][0] = m4.x; rm[k][1] = m4.y; rm[k][2] = m4.z; rm[k][3] = m4.w;
        hm[k][0] = fmaxf(fmaxf(lw,   m4.x), m4.y);
        hm[k][1] = fmaxf(fmaxf(m4.x, m4.y), m4.z);
        hm[k][2] = fmaxf(fmaxf(m4.y, m4.z), m4.w);
        hm[k][3] = fmaxf(fmaxf(m4.z, m4.w), rx);
    }

    bool p[2][4];
    int cntT = 0;
    #pragma unroll
    for (int k = 1; k <= 2; ++k)
        #pragma unroll
        for (int j = 0; j < 4; ++j) {
            const float m9 = fmaxf(fmaxf(hm[k - 1][j], hm[k][j]), hm[k + 1][j]);
            p[k - 1][j] = (rm[k][j] >= m9);
            cntT += p[k - 1][j] ? 1 : 0;
        }

    // wave-level exclusive scan of cntT; one LDS atomic per wave
    int scan = cntT;
    #pragma unroll
    for (int d = 1; d < 64; d <<= 1) {
        const int v = __shfl_up(scan, d, 64);
        if (lane >= d) scan += v;
    }
    int wbase = 0;
    if (lane == 63 && scan > 0) wbase = atomicAdd(&lcnt, scan);
    wbase = __shfl(wbase, 63, 64);
    int mybase = wbase + scan - cntT;

    #pragma unroll
    for (int k = 1; k <= 2; ++k)
        #pragma unroll
        for (int j = 0; j < 4; ++j) {
            if (p[k - 1][j]) {
                const float s = rm[k][j];
                const unsigned idx =
                    (unsigned)((by + 2 * rg + (k - 1)) * IMW + (bx + 4 * c + j));
                const u64 key = ((u64)__float_as_uint(s) << 32) | (unsigned)(~idx);
                if (mybase < LCAP) lcand[mybase] = key;
                mybase++;
            }
        }
    __syncthreads();

    const int m = (lcnt < LCAP) ? lcnt : LCAP;
    if (tid == 0) gbase = atomicAdd(&cnt[b], m);
    __syncthreads();
    const int base = gbase;
    for (int i = tid; i < m; i += 256) {
        const int pp = base + i;
        if (pp < CAP) cand[(size_t)b * CAP + pp] = lcand[i];
    }
}

// ---------------------------------------------------------------------------
// K2: (slice, image) blocks. Block-private LDS histogram of a strided slice,
// plain stores to slicehist — zero global atomics.
// ---------------------------------------------------------------------------
__global__ __launch_bounds__(256)
void slice_hist_kernel(const u64* __restrict__ cand,
                       const int* __restrict__ cnt,
                       unsigned* __restrict__ slicehist) {
    const int slice = blockIdx.x;
    const int b     = blockIdx.y;
    const int tid   = threadIdx.x;

    __shared__ unsigned hist[NB];
    for (int i = tid; i < NB; i += 256) hist[i] = 0;
    __syncthreads();

    int n = cnt[b];
    if (n > CAP) n = CAP;
    const u64* cb = cand + (size_t)b * CAP;
    for (int i = slice * 256 + tid; i < n; i += NSLICE * 256)
        atomicAdd(&hist[(unsigned)(cb[i] >> 52)], 1u);
    __syncthreads();

    unsigned* out = slicehist + (((size_t)b * NSLICE + slice) << 12);
    for (int i = tid; i < NB; i += 256) out[i] = hist[i];
}

// ---------------------------------------------------------------------------
// K2b: 1 block/image. Merge slice hists ONCE, derive exact threshold bin
// bstar + above-count, publish to meta[b].
// ---------------------------------------------------------------------------
__global__ __launch_bounds__(256)
void merge_meta_kernel(const unsigned* __restrict__ slicehist,
                       int* __restrict__ meta) {
    const int b   = blockIdx.x;
    const int tid = threadIdx.x;

    __shared__ unsigned tot[NB];
    __shared__ unsigned sA[256], csS[256];
    __shared__ int bstarS, aboveS;

    const unsigned* shB = slicehist + (((size_t)b * NSLICE) << 12);
    for (int i = tid; i < NB; i += 256) {
        unsigned t = 0;
        #pragma unroll
        for (int s = 0; s < NSLICE; ++s) t += shB[(s << 12) + i];
        tot[i] = t;
    }
    if (tid == 0) { bstarS = 0; aboveS = 0; }
    __syncthreads();

    unsigned cs = 0;
    #pragma unroll
    for (int j = 0; j < 16; ++j) cs += tot[tid * 16 + j];
    csS[tid] = cs;
    sA[tid]  = cs;
    __syncthreads();
    for (int off = 1; off < 256; off <<= 1) {
        const unsigned v = sA[tid] + ((tid + off < 256) ? sA[tid + off] : 0u);
        __syncthreads();
        sA[tid] = v;
        __syncthreads();
    }
    const unsigned total = sA[0];
    if (total > (unsigned)KMAX) {
        const unsigned incl = sA[tid];
        const unsigned excl = incl - csS[tid];
        if (excl < (unsigned)KMAX && incl >= (unsigned)KMAX) {
            unsigned acc = excl;
            int bbin = tid * 16 + 15;
            for (; bbin > tid * 16; --bbin) {
                const unsigned h = tot[bbin];
                if (acc + h >= (unsigned)KMAX) break;
                acc += h;
            }
            bstarS = bbin;
            aboveS = (int)acc;
        }
    }
    __syncthreads();
    if (tid == 0) { meta[b * 2] = bstarS; meta[b * 2 + 1] = aboveS; }
}

// ---------------------------------------------------------------------------
// K3: (slice, image) blocks. Read bstar from meta; compact slice (bin>=bstar)
// into LDS; ONE global atomic/block to flush.
// ---------------------------------------------------------------------------
__global__ __launch_bounds__(256)
void compact_kernel(const u64* __restrict__ cand,
                    const int* __restrict__ cnt,
                    const int* __restrict__ meta,
                    u64* __restrict__ surv,
                    int* __restrict__ scnt) {
    const int slice = blockIdx.x;
    const int b     = blockIdx.y;
    const int tid   = threadIdx.x;
    const int lane  = tid & 63;

    __shared__ u64 lbuf[LBUF];
    __shared__ int lcnt2, gbase2;

    int n = cnt[b];
    if (n > CAP) n = CAP;
    const unsigned bstar = (unsigned)meta[b * 2];
    if (tid == 0) lcnt2 = 0;
    __syncthreads();

    const u64* cb = cand + (size_t)b * CAP;
    for (int i = slice * 256 + tid; i < n; i += NSLICE * 256) {
        const u64 k = cb[i];
        const bool pred = ((unsigned)(k >> 52) >= bstar);
        const u64 mb = __ballot(pred);
        if (mb) {
            const int leader = __ffsll(mb) - 1;
            const int wcount = __popcll(mb);
            const int prefix = __popcll(mb & ((1ull << lane) - 1));
            int wb_ = 0;
            if (lane == leader) wb_ = atomicAdd(&lcnt2, wcount);
            wb_ = __shfl(wb_, leader, 64);
            if (pred) {
                const int pos = wb_ + prefix;
                if (pos < LBUF) lbuf[pos] = k;
            }
        }
    }
    __syncthreads();
    int m = lcnt2;
    if (m > LBUF) m = LBUF;
    if (tid == 0) gbase2 = atomicAdd(&scnt[b], m);
    __syncthreads();
    const int base = gbase2;
    for (int i = tid; i < m; i += 256) {
        const int p = base + i;
        if (p < SURV_CAP) surv[(size_t)b * SURV_CAP + p] = lbuf[i];
    }
}

// ---------------------------------------------------------------------------
// K4: 1 block/image. Split survivors (above-bin -> sel; in-bin -> skeys);
// 13-nibble radix-select (prefix bstar known) -> exact threshold key T;
// collect; bitonic sort desc; ROI epilogue.
// ---------------------------------------------------------------------------
__global__ __launch_bounds__(256)
void finalize_kernel(const u64* __restrict__ surv,
                     const int* __restrict__ scnt,
                     const int* __restrict__ meta,
                     const float* __restrict__ scale,
                     const float* __restrict__ unc,
                     const int* __restrict__ imh,
                     const int* __restrict__ imw,
                     float* __restrict__ rois,
                     float* __restrict__ scoresOut,
                     float* __restrict__ validOut) {
    const int b   = blockIdx.x;
    const int tid = threadIdx.x;

    __shared__ u64 skeys[SKEYS];
    __shared__ u64 sel[KMAX];
    __shared__ unsigned h2[16];
    __shared__ u64 prefS;
    __shared__ int rem2S, cSel, cSk;

    int ns = scnt[b];
    if (ns > SURV_CAP) ns = SURV_CAP;
    const unsigned bstar = (unsigned)meta[b * 2];

    sel[tid] = 0ull;
    if (tid == 0) { cSel = 0; cSk = 0; }
    __syncthreads();

    const u64* sb = surv + (size_t)b * SURV_CAP;
    for (int i = tid; i < ns; i += 256) {
        const u64 k = sb[i];
        if ((unsigned)(k >> 52) > bstar) {
            const int p = atomicAdd(&cSel, 1);
            if (p < KMAX) sel[p] = k;
        } else {
            const int p = atomicAdd(&cSk, 1);
            if (p < SKEYS) skeys[p] = k;
        }
    }
    __syncthreads();
    const int above = cSel;
    int nk = cSk;
    if (nk > SKEYS) nk = SKEYS;
    const int remk = KMAX - above;

    u64 T = 0;
    if (nk > remk) {
        if (tid == 0) { prefS = (u64)bstar; rem2S = remk; }
        __syncthreads();
        for (int p = 12; p >= 0; --p) {
            if (tid < 16) h2[tid] = 0;
            __syncthreads();
            const u64 pre = prefS;
            for (int i = tid; i < nk; i += 256) {
                const u64 k = skeys[i];
                if ((k >> ((p + 1) * 4)) == pre)
                    atomicAdd(&h2[(unsigned)(k >> (p * 4)) & 15u], 1u);
            }
            __syncthreads();
            if (tid == 0) {
                int rem = rem2S;
                int v;
                for (v = 15; v >= 0; --v) {
                    const int hv = (int)h2[v];
                    if (rem <= hv) break;
                    rem -= hv;
                }
                if (v < 0) v = 0;
                prefS = (pre << 4) | (unsigned)v;
                rem2S = rem;
            }
            __syncthreads();
        }
        T = prefS;
    }

    for (int i = tid; i < nk; i += 256) {
        const u64 k = skeys[i];
        if (k >= T) {
            const int p = atomicAdd(&cSel, 1);
            if (p < KMAX) sel[p] = k;
        }
    }
    __syncthreads();

    // bitonic sort descending (keys unique; zeros sink)
    for (int kk = 2; kk <= KMAX; kk <<= 1) {
        for (int j = kk >> 1; j > 0; j >>= 1) {
            const int ixj = tid ^ j;
            if (ixj > tid) {
                const u64 a  = sel[tid];
                const u64 bb = sel[ixj];
                const bool desc = ((tid & kk) == 0);
                if (desc ? (a < bb) : (a > bb)) {
                    sel[tid] = bb;
                    sel[ixj] = a;
                }
            }
            __syncthreads();
        }
    }

    // epilogue
    const u64 k = sel[tid];
    const float value = __uint_as_float((unsigned)(k >> 32));
    const bool valid  = (k != 0ull) && (value > 0.0f);

    float r0 = 0.f, r1 = 0.f, r2 = 0.f, r3 = 0.f, r4 = 0.f, sv = 0.f, vv = 0.f;
    if (valid) {
        const unsigned idx = ~(unsigned)(k & 0xFFFFFFFFull);
        const int y = (int)(idx / IMW);
        const int x = (int)(idx % IMW);
        const float cx = ((float)x + 0.5f) * 4.0f;
        const float cy = ((float)y + 0.5f) * 4.0f;
        const float sg = scale[(size_t)b * IMH * IMW + idx];
        const float uu = unc[(size_t)b * IMH * IMW + idx];
        const float su = sigmoidf_(uu);
        float side = 32.0f + sigmoidf_(sg) * (512.0f - 32.0f);
        side = side * (1.0f + 0.25f * su);
        const float half = side * 0.5f;
        const float fw = (float)imw[0];
        const float fh = (float)imh[0];
        r0 = (float)b;
        r1 = fminf(fmaxf(cx - half, 0.0f), fw - 1.0f);
        r2 = fminf(fmaxf(cy - half, 0.0f), fh - 1.0f);
        r3 = fminf(fmaxf(cx + half, 1.0f), fw);
        r4 = fminf(fmaxf(cy + half, 1.0f), fh);
        sv = value;
        vv = 1.0f;
    }
    float* roiP = rois + ((size_t)b * KMAX + tid) * 5;
    roiP[0] = r0; roiP[1] = r1; roiP[2] = r2; roiP[3] = r3; roiP[4] = r4;
    scoresOut[b * KMAX + tid] = sv;
    validOut[b * KMAX + tid]  = vv;
}

extern "C" void kernel_launch(void* const* d_in, const int* in_sizes, int n_in,
                              void* d_out, int out_size, void* d_ws, size_t ws_size,
                              hipStream_t stream) {
    const float* route = (const float*)d_in[0];
    const float* scale = (const float*)d_in[1];
    const float* unc   = (const float*)d_in[2];
    const int*   imh   = (const int*)d_in[3];
    const int*   imw   = (const int*)d_in[4];

    // ws layout (~15.5 MB):
    // [cand 9.44MB][cnt 128B][scnt 128B][meta 256B][slicehist 4MB][surv 2MB]
    char* ws = (char*)d_ws;
    u64*      cand = (u64*)ws;
    size_t    off  = (size_t)BATCH * CAP * sizeof(u64);
    int*      cnt  = (int*)(ws + off);
    int*      scnt = (int*)(ws + off + 128);
    int*      meta = (int*)(ws + off + 256);
    unsigned* slicehist = (unsigned*)(ws + off + 512);
    u64*      surv = (u64*)(ws + off + 512 + (size_t)BATCH * NSLICE * NB * sizeof(unsigned));

    float* rois      = (float*)d_out;                       // [B, 256, 5]
    float* scoresOut = rois + (size_t)BATCH * KMAX * 5;     // [B, 256]
    float* validOut  = scoresOut + (size_t)BATCH * KMAX;    // [B, 256]

    hipMemsetAsync(cnt, 0, 512, stream);   // cnt + scnt + meta

    dim3 grid1(IMW / TW, IMH / TH, BATCH);
    score_nms_kernel<<<grid1, 256, 0, stream>>>(route, unc, cand, cnt);

    dim3 grid2(NSLICE, BATCH);
    slice_hist_kernel<<<grid2, 256, 0, stream>>>(cand, cnt, slicehist);
    merge_meta_kernel<<<BATCH, 256, 0, stream>>>(slicehist, meta);
    compact_kernel<<<grid2, 256, 0, stream>>>(cand, cnt, meta, surv, scnt);

    finalize_kernel<<<BATCH, 256, 0, stream>>>(surv, scnt, meta, scale, unc,
                                               imh, imw, rois, scoresOut, validOut);
}

// Round 7
// 80.384 us; speedup vs baseline: 4.8174x; 1.3234x over previous
//
#include <hip/hip_runtime.h>
#include <cstdint>
#include <cstddef>

#define BATCH 32
#define IMH 512
#define IMW 512
#define KMAX 256
#define CAP 36864        // per-image candidate capacity (expected ~29.3k)
#define NB 4096          // histogram bins: key bits [63:52]
#define NSLICE 8
#define SURV_CAP 8192    // per-image survivor capacity
#define SKEYS 6144       // finalize LDS cap for bin* keys
#define LBUF 1024        // compact per-block LDS survivor buffer

// K1: register rolling-window NMS. Wave = 256 cols (4/lane), RPW output rows.
#define RPW 8
#define LCAP 2048        // block covers 8192 px; worst-case strict maxima = 2048

typedef unsigned long long u64;

__device__ __forceinline__ float sigmoidf_(float x) {
    return 1.0f / (1.0f + expf(-x));
}
__device__ __forceinline__ float scoref_(float r, float u) {
    const float sg = sigmoidf_(r);
    return sg * sg * (1.0f - 0.35f * sigmoidf_(u));
}

// ---------------------------------------------------------------------------
// K1: fused score + 3x3 NMS, no score LDS. Each wave streams rows y0-1..y0+RPW
// for its 256-col span with 1-row register prefetch; horizontal max3 via
// shuffles (+1-lane edge recompute); vertical via 3-row register window.
// key = (score_bits<<32) | ~idx -> unsigned desc == (score desc, idx asc).
// ---------------------------------------------------------------------------
__global__ __launch_bounds__(256)
void score_nms_kernel(const float* __restrict__ route,
                      const float* __restrict__ unc,
                      u64* __restrict__ cand,
                      int* __restrict__ cnt) {
    const int b    = blockIdx.z;
    const int tid  = threadIdx.x;
    const int w    = tid >> 6;
    const int lane = tid & 63;
    const int y0   = (blockIdx.y * 4 + w) * RPW;
    const int x0   = blockIdx.x * 256 + lane * 4;

    __shared__ u64 lcand[LCAP];
    __shared__ int lcnt, gbase;
    if (tid == 0) lcnt = 0;
    __syncthreads();

    const float* rB = route + (size_t)b * IMH * IMW;
    const float* uB = unc   + (size_t)b * IMH * IMW;

    // wave-edge column owned by this lane (exactly one lane per wave is active)
    int ex = -1;
    if (lane == 0)       ex = x0 - 1;
    else if (lane == 63) ex = x0 + 4;
    const bool eAct = (ex >= 0 && ex < IMW);

    const u64 laneMaskLt = (1ull << lane) - 1ull;

    float sP[4], hP1[4], hP2[4];
    #pragma unroll
    for (int j = 0; j < 4; ++j) { sP[j] = -INFINITY; hP1[j] = -INFINITY; hP2[j] = -INFINITY; }

    const int ylast = y0 + RPW;
    bool v = (y0 - 1 >= 0);
    float4 r4, u4; float er = 0.f, eu = 0.f;
    if (v) {
        r4 = *(const float4*)(rB + (size_t)(y0 - 1) * IMW + x0);
        u4 = *(const float4*)(uB + (size_t)(y0 - 1) * IMW + x0);
        if (eAct) { er = rB[(size_t)(y0 - 1) * IMW + ex]; eu = uB[(size_t)(y0 - 1) * IMW + ex]; }
    }

    for (int y = y0 - 1; y <= ylast; ++y) {
        // prefetch next row
        const int yn = y + 1;
        const bool vn = (yn <= ylast) && (yn < IMH);
        float4 r4n, u4n; float ern = 0.f, eun = 0.f;
        if (vn) {
            r4n = *(const float4*)(rB + (size_t)yn * IMW + x0);
            u4n = *(const float4*)(uB + (size_t)yn * IMW + x0);
            if (eAct) { ern = rB[(size_t)yn * IMW + ex]; eun = uB[(size_t)yn * IMW + ex]; }
        }

        // current row scores + horizontal max3
        float sC[4], hmC[4];
        float es = -INFINITY;
        if (v && eAct) es = scoref_(er, eu);
        if (v) {
            sC[0] = scoref_(r4.x, u4.x);
            sC[1] = scoref_(r4.y, u4.y);
            sC[2] = scoref_(r4.z, u4.z);
            sC[3] = scoref_(r4.w, u4.w);
        } else {
            sC[0] = sC[1] = sC[2] = sC[3] = -INFINITY;
        }
        float lft = __shfl_up(sC[3], 1, 64);
        if (lane == 0) lft = es;
        float rgt = __shfl_down(sC[0], 1, 64);
        if (lane == 63) rgt = es;
        if (v) {
            hmC[0] = fmaxf(fmaxf(lft,   sC[0]), sC[1]);
            hmC[1] = fmaxf(fmaxf(sC[0], sC[1]), sC[2]);
            hmC[2] = fmaxf(fmaxf(sC[1], sC[2]), sC[3]);
            hmC[3] = fmaxf(fmaxf(sC[2], sC[3]), rgt);
        } else {
            hmC[0] = hmC[1] = hmC[2] = hmC[3] = -INFINITY;
        }

        // emit NMS verdict for row y-1 (needs hm of y-2, y-1, y)
        if (y >= y0 + 1) {
            const int yo = y - 1;
            bool p[4]; int cntT = 0;
            #pragma unroll
            for (int j = 0; j < 4; ++j) {
                const float m9 = fmaxf(fmaxf(hP2[j], hP1[j]), hmC[j]);
                p[j] = (sP[j] >= m9);
                cntT += p[j] ? 1 : 0;
            }
            const u64 B0 = __ballot(cntT & 1);
            const u64 B1 = __ballot(cntT & 2);
            const u64 B2 = __ballot(cntT & 4);
            const int total = __popcll(B0) + 2 * __popcll(B1) + 4 * __popcll(B2);
            if (total > 0) {
                const int prefix = __popcll(B0 & laneMaskLt) + 2 * __popcll(B1 & laneMaskLt)
                                 + 4 * __popcll(B2 & laneMaskLt);
                int wbase = 0;
                if (lane == 0) wbase = atomicAdd(&lcnt, total);
                wbase = __shfl(wbase, 0, 64);
                int mb = wbase + prefix;
                #pragma unroll
                for (int j = 0; j < 4; ++j) {
                    if (p[j]) {
                        const unsigned idx = (unsigned)(yo * IMW + (x0 + j));
                        const u64 key = ((u64)__float_as_uint(sP[j]) << 32) | (unsigned)(~idx);
                        if (mb < LCAP) lcand[mb] = key;
                        ++mb;
                    }
                }
            }
        }

        #pragma unroll
        for (int j = 0; j < 4; ++j) { hP2[j] = hP1[j]; hP1[j] = hmC[j]; sP[j] = sC[j]; }
        r4 = r4n; u4 = u4n; er = ern; eu = eun; v = vn;
    }

    __syncthreads();
    const int m = (lcnt < LCAP) ? lcnt : LCAP;
    if (tid == 0) gbase = atomicAdd(&cnt[b], m);
    __syncthreads();
    const int base = gbase;
    for (int i = tid; i < m; i += 256) {
        const int pp = base + i;
        if (pp < CAP) cand[(size_t)b * CAP + pp] = lcand[i];
    }
}

// ---------------------------------------------------------------------------
// K2: (slice, image) blocks. Block-private LDS histogram of a strided slice,
// plain stores to slicehist — zero global atomics.
// ---------------------------------------------------------------------------
__global__ __launch_bounds__(256)
void slice_hist_kernel(const u64* __restrict__ cand,
                       const int* __restrict__ cnt,
                       unsigned* __restrict__ slicehist) {
    const int slice = blockIdx.x;
    const int b     = blockIdx.y;
    const int tid   = threadIdx.x;

    __shared__ unsigned hist[NB];
    for (int i = tid; i < NB; i += 256) hist[i] = 0;
    __syncthreads();

    int n = cnt[b];
    if (n > CAP) n = CAP;
    const u64* cb = cand + (size_t)b * CAP;
    for (int i = slice * 256 + tid; i < n; i += NSLICE * 256)
        atomicAdd(&hist[(unsigned)(cb[i] >> 52)], 1u);
    __syncthreads();

    unsigned* out = slicehist + (((size_t)b * NSLICE + slice) << 12);
    for (int i = tid; i < NB; i += 256) out[i] = hist[i];
}

// ---------------------------------------------------------------------------
// K2b: 1 block/image. Merge slice hists ONCE, derive exact threshold bin
// bstar + above-count, publish to meta[b].
// ---------------------------------------------------------------------------
__global__ __launch_bounds__(256)
void merge_meta_kernel(const unsigned* __restrict__ slicehist,
                       int* __restrict__ meta) {
    const int b   = blockIdx.x;
    const int tid = threadIdx.x;

    __shared__ unsigned tot[NB];
    __shared__ unsigned sA[256], csS[256];
    __shared__ int bstarS, aboveS;

    const unsigned* shB = slicehist + (((size_t)b * NSLICE) << 12);
    for (int i = tid; i < NB; i += 256) {
        unsigned t = 0;
        #pragma unroll
        for (int s = 0; s < NSLICE; ++s) t += shB[(s << 12) + i];
        tot[i] = t;
    }
    if (tid == 0) { bstarS = 0; aboveS = 0; }
    __syncthreads();

    unsigned cs = 0;
    #pragma unroll
    for (int j = 0; j < 16; ++j) cs += tot[tid * 16 + j];
    csS[tid] = cs;
    sA[tid]  = cs;
    __syncthreads();
    for (int off = 1; off < 256; off <<= 1) {
        const unsigned vv = sA[tid] + ((tid + off < 256) ? sA[tid + off] : 0u);
        __syncthreads();
        sA[tid] = vv;
        __syncthreads();
    }
    const unsigned total = sA[0];
    if (total > (unsigned)KMAX) {
        const unsigned incl = sA[tid];
        const unsigned excl = incl - csS[tid];
        if (excl < (unsigned)KMAX && incl >= (unsigned)KMAX) {
            unsigned acc = excl;
            int bbin = tid * 16 + 15;
            for (; bbin > tid * 16; --bbin) {
                const unsigned h = tot[bbin];
                if (acc + h >= (unsigned)KMAX) break;
                acc += h;
            }
            bstarS = bbin;
            aboveS = (int)acc;
        }
    }
    __syncthreads();
    if (tid == 0) { meta[b * 2] = bstarS; meta[b * 2 + 1] = aboveS; }
}

// ---------------------------------------------------------------------------
// K3: (slice, image) blocks. Read bstar from meta; compact slice (bin>=bstar)
// into LDS; ONE global atomic/block to flush.
// ---------------------------------------------------------------------------
__global__ __launch_bounds__(256)
void compact_kernel(const u64* __restrict__ cand,
                    const int* __restrict__ cnt,
                    const int* __restrict__ meta,
                    u64* __restrict__ surv,
                    int* __restrict__ scnt) {
    const int slice = blockIdx.x;
    const int b     = blockIdx.y;
    const int tid   = threadIdx.x;
    const int lane  = tid & 63;

    __shared__ u64 lbuf[LBUF];
    __shared__ int lcnt2, gbase2;

    int n = cnt[b];
    if (n > CAP) n = CAP;
    const unsigned bstar = (unsigned)meta[b * 2];
    if (tid == 0) lcnt2 = 0;
    __syncthreads();

    const u64* cb = cand + (size_t)b * CAP;
    for (int i = slice * 256 + tid; i < n; i += NSLICE * 256) {
        const u64 k = cb[i];
        const bool pred = ((unsigned)(k >> 52) >= bstar);
        const u64 mb = __ballot(pred);
        if (mb) {
            const int leader = __ffsll(mb) - 1;
            const int wcount = __popcll(mb);
            const int prefix = __popcll(mb & ((1ull << lane) - 1));
            int wb_ = 0;
            if (lane == leader) wb_ = atomicAdd(&lcnt2, wcount);
            wb_ = __shfl(wb_, leader, 64);
            if (pred) {
                const int pos = wb_ + prefix;
                if (pos < LBUF) lbuf[pos] = k;
            }
        }
    }
    __syncthreads();
    int m = lcnt2;
    if (m > LBUF) m = LBUF;
    if (tid == 0) gbase2 = atomicAdd(&scnt[b], m);
    __syncthreads();
    const int base = gbase2;
    for (int i = tid; i < m; i += 256) {
        const int p = base + i;
        if (p < SURV_CAP) surv[(size_t)b * SURV_CAP + p] = lbuf[i];
    }
}

// ---------------------------------------------------------------------------
// K4: 1 block/image. Split survivors (above-bin -> sel; in-bin -> skeys);
// 13-nibble radix-select (prefix bstar known) -> exact threshold key T;
// collect; bitonic sort desc; ROI epilogue.
// ---------------------------------------------------------------------------
__global__ __launch_bounds__(256)
void finalize_kernel(const u64* __restrict__ surv,
                     const int* __restrict__ scnt,
                     const int* __restrict__ meta,
                     const float* __restrict__ scale,
                     const float* __restrict__ unc,
                     const int* __restrict__ imh,
                     const int* __restrict__ imw,
                     float* __restrict__ rois,
                     float* __restrict__ scoresOut,
                     float* __restrict__ validOut) {
    const int b   = blockIdx.x;
    const int tid = threadIdx.x;

    __shared__ u64 skeys[SKEYS];
    __shared__ u64 sel[KMAX];
    __shared__ unsigned h2[16];
    __shared__ u64 prefS;
    __shared__ int rem2S, cSel, cSk;

    int ns = scnt[b];
    if (ns > SURV_CAP) ns = SURV_CAP;
    const unsigned bstar = (unsigned)meta[b * 2];

    sel[tid] = 0ull;
    if (tid == 0) { cSel = 0; cSk = 0; }
    __syncthreads();

    const u64* sb = surv + (size_t)b * SURV_CAP;
    for (int i = tid; i < ns; i += 256) {
        const u64 k = sb[i];
        if ((unsigned)(k >> 52) > bstar) {
            const int p = atomicAdd(&cSel, 1);
            if (p < KMAX) sel[p] = k;
        } else {
            const int p = atomicAdd(&cSk, 1);
            if (p < SKEYS) skeys[p] = k;
        }
    }
    __syncthreads();
    const int above = cSel;
    int nk = cSk;
    if (nk > SKEYS) nk = SKEYS;
    const int remk = KMAX - above;

    u64 T = 0;
    if (nk > remk) {
        if (tid == 0) { prefS = (u64)bstar; rem2S = remk; }
        __syncthreads();
        for (int p = 12; p >= 0; --p) {
            if (tid < 16) h2[tid] = 0;
            __syncthreads();
            const u64 pre = prefS;
            for (int i = tid; i < nk; i += 256) {
                const u64 k = skeys[i];
                if ((k >> ((p + 1) * 4)) == pre)
                    atomicAdd(&h2[(unsigned)(k >> (p * 4)) & 15u], 1u);
            }
            __syncthreads();
            if (tid == 0) {
                int rem = rem2S;
                int v;
                for (v = 15; v >= 0; --v) {
                    const int hv = (int)h2[v];
                    if (rem <= hv) break;
                    rem -= hv;
                }
                if (v < 0) v = 0;
                prefS = (pre << 4) | (unsigned)v;
                rem2S = rem;
            }
            __syncthreads();
        }
        T = prefS;
    }

    for (int i = tid; i < nk; i += 256) {
        const u64 k = skeys[i];
        if (k >= T) {
            const int p = atomicAdd(&cSel, 1);
            if (p < KMAX) sel[p] = k;
        }
    }
    __syncthreads();

    // bitonic sort descending (keys unique; zeros sink)
    for (int kk = 2; kk <= KMAX; kk <<= 1) {
        for (int j = kk >> 1; j > 0; j >>= 1) {
            const int ixj = tid ^ j;
            if (ixj > tid) {
                const u64 a  = sel[tid];
                const u64 bb = sel[ixj];
                const bool desc = ((tid & kk) == 0);
                if (desc ? (a < bb) : (a > bb)) {
                    sel[tid] = bb;
                    sel[ixj] = a;
                }
            }
            __syncthreads();
        }
    }

    // epilogue
    const u64 k = sel[tid];
    const float value = __uint_as_float((unsigned)(k >> 32));
    const bool valid  = (k != 0ull) && (value > 0.0f);

    float r0 = 0.f, r1 = 0.f, r2 = 0.f, r3 = 0.f, r4 = 0.f, sv = 0.f, vv = 0.f;
    if (valid) {
        const unsigned idx = ~(unsigned)(k & 0xFFFFFFFFull);
        const int y = (int)(idx / IMW);
        const int x = (int)(idx % IMW);
        const float cx = ((float)x + 0.5f) * 4.0f;
        const float cy = ((float)y + 0.5f) * 4.0f;
        const float sg = scale[(size_t)b * IMH * IMW + idx];
        const float uu = unc[(size_t)b * IMH * IMW + idx];
        const float su = sigmoidf_(uu);
        float side = 32.0f + sigmoidf_(sg) * (512.0f - 32.0f);
        side = side * (1.0f + 0.25f * su);
        const float half = side * 0.5f;
        const float fw = (float)imw[0];
        const float fh = (float)imh[0];
        r0 = (float)b;
        r1 = fminf(fmaxf(cx - half, 0.0f), fw - 1.0f);
        r2 = fminf(fmaxf(cy - half, 0.0f), fh - 1.0f);
        r3 = fminf(fmaxf(cx + half, 1.0f), fw);
        r4 = fminf(fmaxf(cy + half, 1.0f), fh);
        sv = value;
        vv = 1.0f;
    }
    float* roiP = rois + ((size_t)b * KMAX + tid) * 5;
    roiP[0] = r0; roiP[1] = r1; roiP[2] = r2; roiP[3] = r3; roiP[4] = r4;
    scoresOut[b * KMAX + tid] = sv;
    validOut[b * KMAX + tid]  = vv;
}

extern "C" void kernel_launch(void* const* d_in, const int* in_sizes, int n_in,
                              void* d_out, int out_size, void* d_ws, size_t ws_size,
                              hipStream_t stream) {
    const float* route = (const float*)d_in[0];
    const float* scale = (const float*)d_in[1];
    const float* unc   = (const float*)d_in[2];
    const int*   imh   = (const int*)d_in[3];
    const int*   imw   = (const int*)d_in[4];

    // ws layout (~15.5 MB):
    // [cand 9.44MB][cnt 128B][scnt 128B][meta 256B][slicehist 4MB][surv 2MB]
    char* ws = (char*)d_ws;
    u64*      cand = (u64*)ws;
    size_t    off  = (size_t)BATCH * CAP * sizeof(u64);
    int*      cnt  = (int*)(ws + off);
    int*      scnt = (int*)(ws + off + 128);
    int*      meta = (int*)(ws + off + 256);
    unsigned* slicehist = (unsigned*)(ws + off + 512);
    u64*      surv = (u64*)(ws + off + 512 + (size_t)BATCH * NSLICE * NB * sizeof(unsigned));

    float* rois      = (float*)d_out;                       // [B, 256, 5]
    float* scoresOut = rois + (size_t)BATCH * KMAX * 5;     // [B, 256]
    float* validOut  = scoresOut + (size_t)BATCH * KMAX;    // [B, 256]

    hipMemsetAsync(cnt, 0, 512, stream);   // cnt + scnt + meta

    dim3 grid1(2, 16, BATCH);              // col-half, 4-wave row groups, image
    score_nms_kernel<<<grid1, 256, 0, stream>>>(route, unc, cand, cnt);

    dim3 grid2(NSLICE, BATCH);
    slice_hist_kernel<<<grid2, 256, 0, stream>>>(cand, cnt, slicehist);
    merge_meta_kernel<<<BATCH, 256, 0, stream>>>(slicehist, meta);
    compact_kernel<<<grid2, 256, 0, stream>>>(cand, cnt, meta, surv, scnt);

    finalize_kernel<<<BATCH, 256, 0, stream>>>(surv, scnt, meta, scale, unc,
                                               imh, imw, rois, scoresOut, validOut);
}